// Round 1
// baseline (103.425 us; speedup 1.0000x reference)
//
#include <hip/hip_runtime.h>
#include <math.h>

typedef unsigned int u32;
typedef unsigned short u16;
typedef unsigned char u8;
typedef int i32x4 __attribute__((ext_vector_type(4)));
typedef int i32x16 __attribute__((ext_vector_type(16)));

#if __has_builtin(__builtin_amdgcn_mfma_i32_32x32x32_i8)
#define HAS_MFMA_I8 1
#else
#define HAS_MFMA_I8 0
#endif

__device__ __forceinline__ u32 sad8(u32 a, u32 b, u32 c){
#if __has_builtin(__builtin_amdgcn_sad_u8)
    return __builtin_amdgcn_sad_u8(a, b, c);
#else
    u32 s = c;
#pragma unroll
    for (int k = 0; k < 4; ++k){
        int av = (int)((a >> (8*k)) & 255u), bv = (int)((b >> (8*k)) & 255u);
        s += (u32)(av > bv ? av - bv : bv - av);
    }
    return s;
#endif
}

__device__ __forceinline__ u32 hsum16(u32 x, u32 c){ return c + (x & 0xFFFFu) + (x >> 16); }

#if !HAS_MFMA_I8
__device__ __forceinline__ int sdot4(u32 a, u32 b, int c){
#if __has_builtin(__builtin_amdgcn_sdot4)
    return __builtin_amdgcn_sdot4((int)a, (int)b, c, false);
#else
    int s = c;
#pragma unroll
    for (int k = 0; k < 4; ++k){
        int av = (int)(signed char)((a >> (8*k)) & 255u);
        int bv = (int)(signed char)((b >> (8*k)) & 255u);
        s += av * bv;
    }
    return s;
#endif
}
#endif

// ---- prep: q8[row][512] = round(16x)+128 (u8); norms[row] = sum s8^2 (exact int in f32)
__global__ __launch_bounds__(512) void prep_kernel(const float* __restrict__ z,
                                                   const float* __restrict__ zpr,
                                                   u8* __restrict__ q8,
                                                   float* __restrict__ norms){
    const int row  = blockIdx.x*8 + (threadIdx.x >> 6);
    const int lane = threadIdx.x & 63;
    const float* src = (row < 1024) ? (z + (size_t)row*512) : (zpr + (size_t)(row-1024)*512);
    float4 v0 = ((const float4*)src)[2*lane];
    float4 v1 = ((const float4*)src)[2*lane + 1];
    float xs[8] = {v0.x,v0.y,v0.z,v0.w,v1.x,v1.y,v1.z,v1.w};
    u32 b0 = 0, b1 = 0; float s = 0.f;
#pragma unroll
    for (int k = 0; k < 4; ++k){
        u32 qa = (u32)fmaf(xs[k],   16.f, 128.5f) & 255u;
        u32 qb = (u32)fmaf(xs[4+k], 16.f, 128.5f) & 255u;
        b0 |= qa << (8*k);  b1 |= qb << (8*k);
        int sa = (int)qa - 128, sb = (int)qb - 128;
        s += (float)(sa*sa + sb*sb);
    }
    ((uint2*)(q8 + (size_t)row*512))[lane] = make_uint2(b0, b1);
#pragma unroll
    for (int off = 32; off > 0; off >>= 1) s += __shfl_down(s, off);
    if (lane == 0) norms[row] = s;
}

// ---- main: 512 blocks (32 bn x 16 bm), tile 32n x 64m, 512 thr = 8 waves.
// R10: MFMA dp section moved AFTER the sad loop (was before it). dpacc
// (i32x16 = 16 VGPRs) previously stayed live across the entire sad loop,
// putting peak pressure at the __launch_bounds__(512,4) 128-VGPR cliff —
// no slack for the scheduler to pipeline the c-loop ds_reads. Now its live
// range is ~200cy (MFMA cluster -> barrier#2 -> dp LDS write). Also: T5
// setprio around the MFMA cluster, and norms prefetch hoisted before
// barrier #2 so the final-phase global-load latency hides under the
// epilogue LDS phase. Staging/compute math is bit-identical to R9.
// Row stride 20 words (80 B, 16B-aligned): MFMA frag reads conflict-free,
// sad reads 2-way broadcast (free), ds_writes 2-way (free).
#define RS 20
#define L1S 520
__global__ __launch_bounds__(512, 4) void fused_kernel(const u8* __restrict__ q8,
                                                       const float* __restrict__ norms,
                                                       float* __restrict__ out){
    __shared__ u32 smem[15360];   // 61.4 KB: staging [8 waves][96 rows][20 w] / epilogue overlay
    const int t = threadIdx.x;
    const int lane = t & 63;
    const int w = t >> 6;
    const int bn = blockIdx.x & 31;
    const int bm = blockIdx.x >> 5;
    const int n_base = bn*32, m_base = bm*64;

    // ---- stage: wave w's k-slice [64w, 64w+64), 96 rows (32 z + 64 zpr) ----
    u32* wbase = smem + w*1920;
    {
        const int c = lane & 3;              // 16B column
        const int r4 = lane >> 2;            // row within 16-row group
#pragma unroll
        for (int j = 0; j < 6; ++j){
            const int rt = j*16 + r4;        // 0..95
            const int grow = (rt < 32) ? (n_base + rt) : (1024 + m_base + rt - 32);
            uint4 v = *(const uint4*)(q8 + (size_t)grow*512 + 64*w + 16*c);
            *(uint4*)(wbase + rt*RS + 4*c) = v;
        }
    }

    const int tn = lane & 3, tm = lane >> 2;
    u32 acc[8][4];
#pragma unroll
    for (int i = 0; i < 8; ++i)
#pragma unroll
        for (int j = 0; j < 4; ++j) acc[i][j] = 0u;

#if !HAS_MFMA_I8
    int dpa[8][4];
#pragma unroll
    for (int i = 0; i < 8; ++i)
#pragma unroll
        for (int j = 0; j < 4; ++j) dpa[i][j] = 0;
#endif

    __syncthreads();   // barrier #1: all tiles staged (lgkm-tracked ds_writes)

    // ---- sad hot loop: wave w's 64 k, 8n x 4m micro ----
    // (runs first now: only acc + av/bv live -> ~100 VGPRs, scheduler has
    //  headroom to hoist next-c loads)
#pragma unroll
    for (int c = 0; c < 4; ++c){
        uint4 av[8], bv[4];
#pragma unroll
        for (int i = 0; i < 8; ++i)
            av[i] = *(const uint4*)(wbase + (tn + 4*i)*RS + 4*c);
#pragma unroll
        for (int j2 = 0; j2 < 4; ++j2)
            bv[j2] = *(const uint4*)(wbase + (32 + tm + 16*j2)*RS + 4*c);
#pragma unroll
        for (int i = 0; i < 8; ++i)
#pragma unroll
            for (int j2 = 0; j2 < 4; ++j2){
                u32 s = acc[i][j2];
                s = sad8(av[i].x, bv[j2].x, s);
                s = sad8(av[i].y, bv[j2].y, s);
                s = sad8(av[i].z, bv[j2].z, s);
                s = sad8(av[i].w, bv[j2].w, s);
                acc[i][j2] = s;
#if !HAS_MFMA_I8
                int d = dpa[i][j2];
                d = sdot4(av[i].x^0x80808080u, bv[j2].x^0x80808080u, d);
                d = sdot4(av[i].y^0x80808080u, bv[j2].y^0x80808080u, d);
                d = sdot4(av[i].z^0x80808080u, bv[j2].z^0x80808080u, d);
                d = sdot4(av[i].w^0x80808080u, bv[j2].w^0x80808080u, d);
                dpa[i][j2] = d;
#endif
            }
    }

#if HAS_MFMA_I8
    // ---- dp via i8 MFMA: waves 0-3, reads staged LDS (still valid until
    // barrier #2). dpacc live range starts HERE, ends at the dp LDS write.
    i32x16 dpacc = (i32x16)(0);
    const int mt = w & 1;          // m-tile (32 cols) for waves 0-3
    const int kh = w >> 1;         // k-half group for waves 0-3
    const int arow = lane & 31;
    const int brow = 32 + mt*32 + (lane & 31);
    const int o1 = lane >> 5;
    if (w < 4){
        __builtin_amdgcn_s_setprio(1);
#pragma unroll
        for (int s = 0; s < 4; ++s){
            const u32* gb = smem + (kh*4 + s)*1920;
#pragma unroll
            for (int h = 0; h < 2; ++h){
                uint4 a = *(const uint4*)(gb + arow*RS + 8*h + 4*o1);
                uint4 b = *(const uint4*)(gb + brow*RS + 8*h + 4*o1);
                uint4 ax = make_uint4(a.x^0x80808080u, a.y^0x80808080u, a.z^0x80808080u, a.w^0x80808080u);
                uint4 bx = make_uint4(b.x^0x80808080u, b.y^0x80808080u, b.z^0x80808080u, b.w^0x80808080u);
                dpacc = __builtin_amdgcn_mfma_i32_32x32x32_i8(__builtin_bit_cast(i32x4, ax),
                                                              __builtin_bit_cast(i32x4, bx),
                                                              dpacc, 0, 0, 0);
            }
        }
        __builtin_amdgcn_s_setprio(0);
    }
#endif

    // ---- prefetch final-phase norms (global/L2, no LDS dep): latency hides
    // under barrier #2 + epilogue LDS writes.
    const int m  = t >> 3;
    const int n0 = 4*(t & 7);
    float4 nz4 = *(const float4*)&norms[n_base + n0];
    const float np = norms[1024 + m_base + m];

    __syncthreads();   // barrier #2: all reads done; staging region now dead

    // ---- epilogue (overlays staging) ----
    u16*   l1b  = (u16*)smem;                  // [32 n][520] u16
    float* dpbA = (float*)(smem + 8320);       // [32][65]
    float* dpbB = (float*)(smem + 10400);      // [32][65]

#pragma unroll
    for (int i = 0; i < 8; ++i)
#pragma unroll
        for (int j = 0; j < 4; ++j)
            l1b[(tn + 4*i)*L1S + (tm + 16*j)*8 + w] = (u16)acc[i][j];

#if HAS_MFMA_I8
    if (w < 4){
        float* dpb = kh ? dpbB : dpbA;
        const int mcol = mt*32 + (lane & 31);
#pragma unroll
        for (int reg = 0; reg < 16; ++reg){
            const int n = (reg & 3) + 8*(reg >> 2) + 4*(lane >> 5);
            dpb[n*65 + mcol] = (float)dpacc[reg];
        }
    }
#endif
    __syncthreads();

    const float nzv[4] = {nz4.x, nz4.y, nz4.z, nz4.w};

    float l1q[4], dpq[4];
#pragma unroll
    for (int i = 0; i < 4; ++i){
        const int n = n0 + i;
        uint4 lp = *(const uint4*)&l1b[n*L1S + m*8];
        u32 s = hsum16(lp.x, 0u); s = hsum16(lp.y, s);
        s = hsum16(lp.z, s);      s = hsum16(lp.w, s);
        l1q[i] = (float)s;
#if HAS_MFMA_I8
        dpq[i] = dpbA[n*65 + m] + dpbB[n*65 + m];
#else
        dpq[i] = 0.f;
#endif
    }

#if !HAS_MFMA_I8
    {
        float* dpf = (float*)(smem + 8320);   // [2048][2]
#pragma unroll
        for (int ph = 0; ph < 4; ++ph){
            __syncthreads();
            if ((w >> 1) == ph){
#pragma unroll
                for (int i = 0; i < 8; ++i)
#pragma unroll
                    for (int j = 0; j < 4; ++j)
                        dpf[((tn + 4*i)*64 + tm + 16*j)*2 + (w & 1)] = (float)dpa[i][j];
            }
            __syncthreads();
#pragma unroll
            for (int i = 0; i < 4; ++i){
                const int cell = (n0 + i)*64 + m;
                dpq[i] += dpf[cell*2] + dpf[cell*2 + 1];
            }
        }
    }
#endif

    float ov[12];
#pragma unroll
    for (int i = 0; i < 4; ++i){
        const float l2q = nzv[i] + np - 2.f*dpq[i];
        ov[3*i]     = l1q[i] * 0.0625f;
        ov[3*i + 1] = sqrtf(fmaxf(l2q, 0.f)) * 0.0625f;
        ov[3*i + 2] = dpq[i] * 0.00390625f;
    }
    float4* op = (float4*)(out + (((size_t)(m_base + m))*1024 + n_base + n0)*3);
    op[0] = make_float4(ov[0], ov[1], ov[2],  ov[3]);
    op[1] = make_float4(ov[4], ov[5], ov[6],  ov[7]);
    op[2] = make_float4(ov[8], ov[9], ov[10], ov[11]);
}

extern "C" void kernel_launch(void* const* d_in, const int* in_sizes, int n_in,
                              void* d_out, int out_size, void* d_ws, size_t ws_size,
                              hipStream_t stream) {
    const float* z   = (const float*)d_in[0];
    const float* zpr = (const float*)d_in[1];
    float* out = (float*)d_out;
    u8*    q8  = (u8*)d_ws;                            // 1 MB
    float* nrm = (float*)((char*)d_ws + (1 << 20));    // 8 KB

    prep_kernel<<<256, 512, 0, stream>>>(z, zpr, q8, nrm);
    fused_kernel<<<512, 512, 0, stream>>>(q8, nrm, out);
}

// Round 2
// 70.877 us; speedup vs baseline: 1.4592x; 1.4592x over previous
//
#include <hip/hip_runtime.h>
#include <math.h>

typedef unsigned int u32;
typedef unsigned short u16;
typedef unsigned char u8;
typedef int i32x4 __attribute__((ext_vector_type(4)));
typedef int i32x16 __attribute__((ext_vector_type(16)));

#if __has_builtin(__builtin_amdgcn_mfma_i32_32x32x32_i8)
#define HAS_MFMA_I8 1
#else
#define HAS_MFMA_I8 0
#endif

__device__ __forceinline__ u32 sad8(u32 a, u32 b, u32 c){
#if __has_builtin(__builtin_amdgcn_sad_u8)
    return __builtin_amdgcn_sad_u8(a, b, c);
#else
    u32 s = c;
#pragma unroll
    for (int k = 0; k < 4; ++k){
        int av = (int)((a >> (8*k)) & 255u), bv = (int)((b >> (8*k)) & 255u);
        s += (u32)(av > bv ? av - bv : bv - av);
    }
    return s;
#endif
}

__device__ __forceinline__ u32 hsum16(u32 x, u32 c){ return c + (x & 0xFFFFu) + (x >> 16); }

#if !HAS_MFMA_I8
__device__ __forceinline__ int sdot4(u32 a, u32 b, int c){
#if __has_builtin(__builtin_amdgcn_sdot4)
    return __builtin_amdgcn_sdot4((int)a, (int)b, c, false);
#else
    int s = c;
#pragma unroll
    for (int k = 0; k < 4; ++k){
        int av = (int)(signed char)((a >> (8*k)) & 255u);
        int bv = (int)(signed char)((b >> (8*k)) & 255u);
        s += av * bv;
    }
    return s;
#endif
}
#endif

// ---- prep: q8[row][512] = round(16x)+128 (u8); norms[row] = sum s8^2 (exact int in f32)
__global__ __launch_bounds__(512) void prep_kernel(const float* __restrict__ z,
                                                   const float* __restrict__ zpr,
                                                   u8* __restrict__ q8,
                                                   float* __restrict__ norms){
    const int row  = blockIdx.x*8 + (threadIdx.x >> 6);
    const int lane = threadIdx.x & 63;
    const float* src = (row < 1024) ? (z + (size_t)row*512) : (zpr + (size_t)(row-1024)*512);
    float4 v0 = ((const float4*)src)[2*lane];
    float4 v1 = ((const float4*)src)[2*lane + 1];
    float xs[8] = {v0.x,v0.y,v0.z,v0.w,v1.x,v1.y,v1.z,v1.w};
    u32 b0 = 0, b1 = 0; float s = 0.f;
#pragma unroll
    for (int k = 0; k < 4; ++k){
        u32 qa = (u32)fmaf(xs[k],   16.f, 128.5f) & 255u;
        u32 qb = (u32)fmaf(xs[4+k], 16.f, 128.5f) & 255u;
        b0 |= qa << (8*k);  b1 |= qb << (8*k);
        int sa = (int)qa - 128, sb = (int)qb - 128;
        s += (float)(sa*sa + sb*sb);
    }
    ((uint2*)(q8 + (size_t)row*512))[lane] = make_uint2(b0, b1);
#pragma unroll
    for (int off = 32; off > 0; off >>= 1) s += __shfl_down(s, off);
    if (lane == 0) norms[row] = s;
}

// ---- main: 512 blocks (32 bn x 16 bm), tile 32n x 64m, 512 thr = 8 waves.
// R11: back to R9's proven phase order (MFMA before sad loop). Two changes,
// both register-pressure-targeted, motivated by R10's counters (VGPR_Count=64,
// WRITE_SIZE=117MB -> ~100 dwords/thread spilled to scratch):
//  (a) amdgpu_waves_per_eu(4,4): __launch_bounds__(512,4) only sets a MIN;
//      the backend was free to target 8 waves/EU (64-VGPR budget) and spill,
//      even though 61.4KB LDS already caps the CU at 2 blocks (16 waves).
//      Pinning min=max=4 makes 128 VGPRs the explicit target.
//  (b) sad loop loads av in two halves of 4 (live set ~100 regs, was ~127
//      right at the 128 cliff). Same addresses, same math, reordered only.
// Row stride 20 words (80 B, 16B-aligned): MFMA frag reads conflict-free,
// sad reads 2-way broadcast (free), ds_writes 2-way (free).
#define RS 20
#define L1S 520
__global__ __launch_bounds__(512)
__attribute__((amdgpu_waves_per_eu(4, 4)))
void fused_kernel(const u8* __restrict__ q8,
                  const float* __restrict__ norms,
                  float* __restrict__ out){
    __shared__ u32 smem[15360];   // 61.4 KB: staging [8 waves][96 rows][20 w] / epilogue overlay
    const int t = threadIdx.x;
    const int lane = t & 63;
    const int w = t >> 6;
    const int bn = blockIdx.x & 31;
    const int bm = blockIdx.x >> 5;
    const int n_base = bn*32, m_base = bm*64;

    // ---- stage: wave w's k-slice [64w, 64w+64), 96 rows (32 z + 64 zpr) ----
    u32* wbase = smem + w*1920;
    {
        const int c = lane & 3;              // 16B column
        const int r4 = lane >> 2;            // row within 16-row group
#pragma unroll
        for (int j = 0; j < 6; ++j){
            const int rt = j*16 + r4;        // 0..95
            const int grow = (rt < 32) ? (n_base + rt) : (1024 + m_base + rt - 32);
            uint4 v = *(const uint4*)(q8 + (size_t)grow*512 + 64*w + 16*c);
            *(uint4*)(wbase + rt*RS + 4*c) = v;
        }
    }

    const int tn = lane & 3, tm = lane >> 2;
    u32 acc[8][4];
#pragma unroll
    for (int i = 0; i < 8; ++i)
#pragma unroll
        for (int j = 0; j < 4; ++j) acc[i][j] = 0u;

#if HAS_MFMA_I8
    i32x16 dpacc = (i32x16)(0);
    const int mt = w & 1;          // m-tile (32 cols) for waves 0-3
    const int kh = w >> 1;         // k-half group for waves 0-3
    const int arow = lane & 31;
    const int brow = 32 + mt*32 + (lane & 31);
    const int o1 = lane >> 5;
#else
    int dpa[8][4];
#pragma unroll
    for (int i = 0; i < 8; ++i)
#pragma unroll
        for (int j = 0; j < 4; ++j) dpa[i][j] = 0;
#endif

    __syncthreads();   // barrier #1: all tiles staged (lgkm-tracked ds_writes)

#if HAS_MFMA_I8
    if (w < 4){
#pragma unroll
        for (int s = 0; s < 4; ++s){
            const u32* gb = smem + (kh*4 + s)*1920;
#pragma unroll
            for (int h = 0; h < 2; ++h){
                uint4 a = *(const uint4*)(gb + arow*RS + 8*h + 4*o1);
                uint4 b = *(const uint4*)(gb + brow*RS + 8*h + 4*o1);
                uint4 ax = make_uint4(a.x^0x80808080u, a.y^0x80808080u, a.z^0x80808080u, a.w^0x80808080u);
                uint4 bx = make_uint4(b.x^0x80808080u, b.y^0x80808080u, b.z^0x80808080u, b.w^0x80808080u);
                dpacc = __builtin_amdgcn_mfma_i32_32x32x32_i8(__builtin_bit_cast(i32x4, ax),
                                                              __builtin_bit_cast(i32x4, bx),
                                                              dpacc, 0, 0, 0);
            }
        }
    }
#endif

    // ---- sad hot loop: wave w's 64 k, 8n x 4m micro (av loaded in halves) ----
#pragma unroll
    for (int c = 0; c < 4; ++c){
        uint4 bv[4];
#pragma unroll
        for (int j2 = 0; j2 < 4; ++j2)
            bv[j2] = *(const uint4*)(wbase + (32 + tm + 16*j2)*RS + 4*c);
#pragma unroll
        for (int ih = 0; ih < 2; ++ih){
            uint4 av[4];
#pragma unroll
            for (int i = 0; i < 4; ++i)
                av[i] = *(const uint4*)(wbase + (tn + 4*(4*ih + i))*RS + 4*c);
#pragma unroll
            for (int i = 0; i < 4; ++i)
#pragma unroll
                for (int j2 = 0; j2 < 4; ++j2){
                    u32 s = acc[4*ih + i][j2];
                    s = sad8(av[i].x, bv[j2].x, s);
                    s = sad8(av[i].y, bv[j2].y, s);
                    s = sad8(av[i].z, bv[j2].z, s);
                    s = sad8(av[i].w, bv[j2].w, s);
                    acc[4*ih + i][j2] = s;
#if !HAS_MFMA_I8
                    int d = dpa[4*ih + i][j2];
                    d = sdot4(av[i].x^0x80808080u, bv[j2].x^0x80808080u, d);
                    d = sdot4(av[i].y^0x80808080u, bv[j2].y^0x80808080u, d);
                    d = sdot4(av[i].z^0x80808080u, bv[j2].z^0x80808080u, d);
                    d = sdot4(av[i].w^0x80808080u, bv[j2].w^0x80808080u, d);
                    dpa[4*ih + i][j2] = d;
#endif
                }
        }
    }
    __syncthreads();   // barrier #2: all reads done; staging region now dead

    // ---- epilogue (overlays staging) ----
    u16*   l1b  = (u16*)smem;                  // [32 n][520] u16
    float* dpbA = (float*)(smem + 8320);       // [32][65]
    float* dpbB = (float*)(smem + 10400);      // [32][65]

#pragma unroll
    for (int i = 0; i < 8; ++i)
#pragma unroll
        for (int j = 0; j < 4; ++j)
            l1b[(tn + 4*i)*L1S + (tm + 16*j)*8 + w] = (u16)acc[i][j];

#if HAS_MFMA_I8
    if (w < 4){
        float* dpb = kh ? dpbB : dpbA;
        const int mcol = mt*32 + (lane & 31);
#pragma unroll
        for (int reg = 0; reg < 16; ++reg){
            const int n = (reg & 3) + 8*(reg >> 2) + 4*(lane >> 5);
            dpb[n*65 + mcol] = (float)dpacc[reg];
        }
    }
#endif
    __syncthreads();

    const int m  = t >> 3;
    const int n0 = 4*(t & 7);
    float4 nz4 = *(const float4*)&norms[n_base + n0];
    const float np = norms[1024 + m_base + m];
    const float nzv[4] = {nz4.x, nz4.y, nz4.z, nz4.w};

    float l1q[4], dpq[4];
#pragma unroll
    for (int i = 0; i < 4; ++i){
        const int n = n0 + i;
        uint4 lp = *(const uint4*)&l1b[n*L1S + m*8];
        u32 s = hsum16(lp.x, 0u); s = hsum16(lp.y, s);
        s = hsum16(lp.z, s);      s = hsum16(lp.w, s);
        l1q[i] = (float)s;
#if HAS_MFMA_I8
        dpq[i] = dpbA[n*65 + m] + dpbB[n*65 + m];
#else
        dpq[i] = 0.f;
#endif
    }

#if !HAS_MFMA_I8
    {
        float* dpf = (float*)(smem + 8320);   // [2048][2]
#pragma unroll
        for (int ph = 0; ph < 4; ++ph){
            __syncthreads();
            if ((w >> 1) == ph){
#pragma unroll
                for (int i = 0; i < 8; ++i)
#pragma unroll
                    for (int j = 0; j < 4; ++j)
                        dpf[((tn + 4*i)*64 + tm + 16*j)*2 + (w & 1)] = (float)dpa[i][j];
            }
            __syncthreads();
#pragma unroll
            for (int i = 0; i < 4; ++i){
                const int cell = (n0 + i)*64 + m;
                dpq[i] += dpf[cell*2] + dpf[cell*2 + 1];
            }
        }
    }
#endif

    float ov[12];
#pragma unroll
    for (int i = 0; i < 4; ++i){
        const float l2q = nzv[i] + np - 2.f*dpq[i];
        ov[3*i]     = l1q[i] * 0.0625f;
        ov[3*i + 1] = sqrtf(fmaxf(l2q, 0.f)) * 0.0625f;
        ov[3*i + 2] = dpq[i] * 0.00390625f;
    }
    float4* op = (float4*)(out + (((size_t)(m_base + m))*1024 + n_base + n0)*3);
    op[0] = make_float4(ov[0], ov[1], ov[2],  ov[3]);
    op[1] = make_float4(ov[4], ov[5], ov[6],  ov[7]);
    op[2] = make_float4(ov[8], ov[9], ov[10], ov[11]);
}

extern "C" void kernel_launch(void* const* d_in, const int* in_sizes, int n_in,
                              void* d_out, int out_size, void* d_ws, size_t ws_size,
                              hipStream_t stream) {
    const float* z   = (const float*)d_in[0];
    const float* zpr = (const float*)d_in[1];
    float* out = (float*)d_out;
    u8*    q8  = (u8*)d_ws;                            // 1 MB
    float* nrm = (float*)((char*)d_ws + (1 << 20));    // 8 KB

    prep_kernel<<<256, 512, 0, stream>>>(z, zpr, q8, nrm);
    fused_kernel<<<512, 512, 0, stream>>>(q8, nrm, out);
}